// Round 3
// baseline (772.481 us; speedup 1.0000x reference)
//
#include <hip/hip_runtime.h>

#define B_    32
#define M_    512
#define W_    8
#define QL    32
#define NC    8
#define CL    8
#define EMB   768
#define MDIM  256
#define VOCAB 50000
#define NV    288   // 32 question vectors + 256 (c,b) answer vectors

// X/O/P row layout: row v: v in [0,32) -> question vec b=v
//                          v = 32 + c*32 + b -> answer vec (c,b)

__global__ __launch_bounds__(768) void init_ua(const float* __restrict__ Btab,
        const int* __restrict__ ques, const int* __restrict__ ac,
        float* __restrict__ X){
    int v = blockIdx.x, d = threadIdx.x;
    float acc = 0.f;
    if (v < 32){
        const int* q = ques + v*QL;
        for (int i=0;i<QL;i++) acc += Btab[(size_t)q[i]*EMB + d];
    } else {
        int c = (v-32)>>5, b = (v-32)&31;
        const int* q = ac + (b*NC + c)*CL;
        for (int i=0;i<CL;i++) acc += Btab[(size_t)q[i]*EMB + d];
    }
    X[(size_t)v*EMB + d] = acc;
}

// C[r0+r][c0+c] = sum_k X[r0+r][k] * (tB ? T[c0+c][k] : T[k][c0+c])
// 32-row x 64-col tile per block, K chunks of 64.
__global__ __launch_bounds__(256) void proj_gemm(const float* __restrict__ X,
        const float* __restrict__ T0, const float* __restrict__ T1,
        float* __restrict__ C, int tB){
    __shared__ float Xs[32*64];
    __shared__ float Ts[64*65];
    int cb = blockIdx.x, rb = blockIdx.y;
    const float* T = (rb==0) ? T0 : T1;
    int tid = threadIdx.x;
    int col = tid & 63, rg = tid >> 6;
    int c0 = cb*64, r0 = rb*32;
    float acc[8] = {0,0,0,0,0,0,0,0};
    for (int k0=0;k0<EMB;k0+=64){
        #pragma unroll
        for (int i=0;i<8;i++){
            int eid = i*256 + tid;
            int r = eid>>6, k = eid&63;
            Xs[r*64+k] = X[(size_t)(r0+r)*EMB + k0+k];
        }
        if (tB){
            #pragma unroll
            for (int i=0;i<16;i++){      // 64 rows of Ts: 16 x 4 row-groups
                int c = i*4 + rg;
                Ts[c*65 + col] = T[(size_t)(c0+c)*EMB + k0+col];
            }
        } else {
            #pragma unroll
            for (int i=0;i<16;i++){      // 64 rows of Ts: 16 x 4 row-groups
                int k = i*4 + rg;
                Ts[k*65 + col] = T[(size_t)(k0+k)*EMB + c0+col];
            }
        }
        __syncthreads();
        #pragma unroll
        for (int k=0;k<64;k++){
            float tv = tB ? Ts[col*65 + k] : Ts[k*65 + col];
            #pragma unroll
            for (int i=0;i<8;i++)
                acc[i] += Xs[(rg*8+i)*64 + k] * tv;
        }
        __syncthreads();
    }
    #pragma unroll
    for (int i=0;i<8;i++)
        C[(size_t)(r0+rg*8+i)*EMB + c0+col] = acc[i];
}

// scores: SC[v][m] = sum over 768 of emb(A)[b,m,:] . P[v,:]
// one wave handles 4 m's; gathers 24 rows per m; 9 projections in regs per slot.
__global__ __launch_bounds__(256) void scores_kernel(const float* __restrict__ A,
        const float* __restrict__ P,
        const int* __restrict__ subj, const int* __restrict__ rel,
        const int* __restrict__ obj, float* __restrict__ SC){
    int b = blockIdx.x, mc = blockIdx.y;
    int wave = threadIdx.x >> 6, lane = threadIdx.x & 63;
    int m0 = mc*16 + wave*4;
    float acc[4][9];
    #pragma unroll
    for (int i=0;i<4;i++)
        #pragma unroll
        for (int j=0;j<9;j++) acc[i][j]=0.f;
    #pragma unroll 1
    for (int slot=0; slot<3; ++slot){
        const int* base = (slot==0) ? subj : (slot==1) ? rel : obj;
        float4 pj[9];
        pj[0] = *(const float4*)(P + (size_t)b*EMB + slot*256 + lane*4);
        #pragma unroll
        for (int c=0;c<8;c++)
            pj[c+1] = *(const float4*)(P + (size_t)(32 + c*32 + b)*EMB + slot*256 + lane*4);
        const int* ids = base + (b*M_ + m0)*W_;
        #pragma unroll
        for (int mi=0;mi<4;mi++){
            #pragma unroll
            for (int w=0;w<W_;w++){
                int idx = ids[mi*W_ + w];
                float4 rv = *(const float4*)(A + (size_t)idx*MDIM + lane*4);
                #pragma unroll
                for (int j=0;j<9;j++)
                    acc[mi][j] += rv.x*pj[j].x + rv.y*pj[j].y
                                + rv.z*pj[j].z + rv.w*pj[j].w;
            }
        }
    }
    #pragma unroll
    for (int mi=0;mi<4;mi++){
        #pragma unroll
        for (int j=0;j<9;j++){
            float v = acc[mi][j];
            #pragma unroll
            for (int off=32;off;off>>=1) v += __shfl_xor(v, off, 64);
            if (lane==0){
                int vr = (j==0) ? b : 32 + (j-1)*32 + b;
                SC[(size_t)vr*M_ + m0+mi] = v;
            }
        }
    }
}

// renorm rows of SC in place. v<32 -> question variant, else answer variant.
__global__ __launch_bounds__(256) void renorm_kernel(float* __restrict__ SC){
    int v = blockIdx.x, tid = threadIdx.x;
    float* row = SC + (size_t)v*M_;
    __shared__ float red[256];
    float s0 = row[tid], s1 = row[tid+256];
    float m = fmaxf(s0,s1);
    red[tid]=m; __syncthreads();
    for (int o=128;o;o>>=1){ if (tid<o) red[tid]=fmaxf(red[tid],red[tid+o]); __syncthreads(); }
    m = red[0]; __syncthreads();
    float e = expf(s0-m)+expf(s1-m);
    red[tid]=e; __syncthreads();
    for (int o=128;o;o>>=1){ if (tid<o) red[tid]+=red[tid+o]; __syncthreads(); }
    float lse = logf(red[0]); __syncthreads();
    float p0 = s0-m-lse, p1 = s1-m-lse;
    if (v < 32){
        red[tid]=fminf(p0,p1); __syncthreads();
        for (int o=128;o;o>>=1){ if (tid<o) red[tid]=fminf(red[tid],red[tid+o]); __syncthreads(); }
        float mn = red[0]; __syncthreads();
        p0 -= mn; p1 -= mn;
        red[tid]=fabsf(p0+1e-8f)+fabsf(p1+1e-8f); __syncthreads();
        for (int o=128;o;o>>=1){ if (tid<o) red[tid]+=red[tid+o]; __syncthreads(); }
        float nrm = red[0];
        p0 /= nrm; p1 /= nrm;
    } else {
        red[tid]=fabsf(p0)+fabsf(p1); __syncthreads();
        for (int o=128;o;o>>=1){ if (tid<o) red[tid]+=red[tid+o]; __syncthreads(); }
        float nrm = red[0];
        if (nrm == 0.f){ p0 += 1.f; p1 += 1.f; nrm = 512.f; }
        p0 /= nrm; p1 /= nrm;
    }
    row[tid]=p0; row[tid+256]=p1;
}

// o-step partials: block (b, slot, chunk-of-64-m); thread owns one d of the slot
// segment; 9 weighted accumulations per gathered element.
__global__ __launch_bounds__(256) void o_kernel(const float* __restrict__ A,
        const float* __restrict__ SC,
        const int* __restrict__ subj, const int* __restrict__ rel,
        const int* __restrict__ obj, float* __restrict__ Opart){
    int b = blockIdx.x, slot = blockIdx.y, chunk = blockIdx.z;
    int tid = threadIdx.x;
    __shared__ float pl[9*64];
    int m0 = chunk*64;
    for (int t=tid; t<9*64; t+=256){
        int j = t>>6, mi = t&63;
        int vr = (j==0) ? b : 32 + (j-1)*32 + b;
        pl[t] = SC[(size_t)vr*M_ + m0+mi];
    }
    __syncthreads();
    const int* ids = ((slot==0)?subj:(slot==1)?rel:obj) + (b*M_+m0)*W_;
    float acc[9] = {0,0,0,0,0,0,0,0,0};
    for (int mi=0;mi<64;mi++){
        #pragma unroll
        for (int w=0;w<W_;w++){
            int idx = ids[mi*W_+w];
            float val = A[(size_t)idx*MDIM + tid];
            #pragma unroll
            for (int j=0;j<9;j++) acc[j] += pl[j*64+mi]*val;
        }
    }
    #pragma unroll
    for (int j=0;j<9;j++){
        int vr = (j==0) ? b : 32 + (j-1)*32 + b;
        Opart[((size_t)chunk*NV + vr)*EMB + slot*256 + tid] = acc[j];
    }
}

__global__ __launch_bounds__(256) void update_kernel(const float* __restrict__ Opart,
        float* __restrict__ O, float* __restrict__ X){
    int i = blockIdx.x*256 + threadIdx.x; // over NV*EMB
    float s = 0.f;
    #pragma unroll
    for (int c=0;c<8;c++) s += Opart[(size_t)c*NV*EMB + i];
    O[i] = s;
    X[i] += s;
}

__global__ __launch_bounds__(256) void pred_kernel(const float* __restrict__ qW,
        const float* __restrict__ O, float* __restrict__ out){
    int pair = blockIdx.x*4 + (threadIdx.x>>6);
    int lane = threadIdx.x & 63;
    int c = pair >> 5, b = pair & 31;
    const float* oa = O + (size_t)(32 + c*32 + b)*EMB;
    const float* q  = qW + (size_t)b*EMB;
    float acc = 0.f;
    for (int k=lane;k<EMB;k+=64) acc += q[k]*oa[k];
    #pragma unroll
    for (int off=32;off;off>>=1) acc += __shfl_xor(acc, off, 64);
    if (lane==0) out[b*NC + c] = acc;
}

extern "C" void kernel_launch(void* const* d_in, const int* in_sizes, int n_in,
                              void* d_out, int out_size, void* d_ws, size_t ws_size,
                              hipStream_t stream){
    const int*   subj = (const int*)d_in[0];
    const int*   rel  = (const int*)d_in[1];
    const int*   obj  = (const int*)d_in[2];
    const int*   ques = (const int*)d_in[3];
    const int*   ac   = (const int*)d_in[4];
    const float* At   = (const float*)d_in[5];
    const float* Bt   = (const float*)d_in[6];
    const float* U    = (const float*)d_in[7];
    const float* V    = (const float*)d_in[8];
    const float* Wm   = (const float*)d_in[9];
    float* out = (float*)d_out;

    float* X  = (float*)d_ws;        // 288*768
    float* P  = X  + NV*EMB;         // 288*768
    float* SC = P  + NV*EMB;         // 288*512
    float* O  = SC + NV*M_;          // 288*768
    float* Op = O  + NV*EMB;         // 8*288*768
    float* qW = Op + 8*NV*EMB;       // 32*768

    init_ua<<<NV, 768, 0, stream>>>(Bt, ques, ac, X);
    const size_t TBL = (size_t)VOCAB*MDIM;
    for (int h=0; h<2; ++h){
        proj_gemm<<<dim3(12,9), 256, 0, stream>>>(X, U, V, P, 1);
        scores_kernel<<<dim3(32,32), 256, 0, stream>>>(At + (size_t)h*TBL, P, subj, rel, obj, SC);
        renorm_kernel<<<NV, 256, 0, stream>>>(SC);
        o_kernel<<<dim3(32,3,8), 256, 0, stream>>>(At + (size_t)(h+1)*TBL, SC, subj, rel, obj, Op);
        update_kernel<<<NV*EMB/256, 256, 0, stream>>>(Op, O, X);
    }
    proj_gemm<<<dim3(12,1), 256, 0, stream>>>(O, Wm, Wm, qW, 0);
    pred_kernel<<<64, 256, 0, stream>>>(qW, O, out);
}